// Round 8
// baseline (442.507 us; speedup 1.0000x reference)
//
#include <hip/hip_runtime.h>
#include <cstdint>
#include <cstddef>

#define N_NODES 12288
#define IN_F 256
#define OUT_F 128
#define BM 16
#define BK 256                      /* K bytes (fp8) per step */
#define NSTEPS (N_NODES / BK)       /* 48 */

using f32x4 = __attribute__((ext_vector_type(4))) float;
typedef long long i64;

// ---------------------------------------------------------------- deg pass
// dinv[i] = rsqrt(1 + sum_j adj[i][j]); also writes adjq = e4m3(adj).
// adj loads are NON-TEMPORAL (604 MB streamed once; don't thrash L3) so the
// 151 MB adjq written here stays L3-resident for k_gemm's re-read.
__global__ __launch_bounds__(256) void k_deg(const float* __restrict__ adj,
                                             float* __restrict__ dinv,
                                             unsigned int* __restrict__ adjq) {
  const size_t row = blockIdx.x;
  const f32x4* p = reinterpret_cast<const f32x4*>(adj + row * N_NODES) + threadIdx.x;
  unsigned int* q = adjq + row * (N_NODES / 4) + threadIdx.x;
  float s = 0.f;
#pragma unroll
  for (int i = 0; i < (N_NODES / 4) / 256; ++i) {
    f32x4 v = __builtin_nontemporal_load(p + (size_t)i * 256);
    s += (v[0] + v[1]) + (v[2] + v[3]);
    unsigned int u = (unsigned)__builtin_amdgcn_cvt_pk_fp8_f32(v[0], v[1], 0, false);
    u = (unsigned)__builtin_amdgcn_cvt_pk_fp8_f32(v[2], v[3], (int)u, true);
    q[(size_t)i * 256] = u;
  }
#pragma unroll
  for (int off = 32; off >= 1; off >>= 1) s += __shfl_down(s, off, 64);
  __shared__ float red[4];
  const int lane = threadIdx.x & 63, w = threadIdx.x >> 6;
  if (lane == 0) red[w] = s;
  __syncthreads();
  if (threadIdx.x == 0) {
    float tot = (red[0] + red[1]) + (red[2] + red[3]) + 1.0f;
    dinv[row] = rsqrtf(tot);
  }
}

// ------------------------------------------------------------- support pass
// ssc[j][o] = dinv[j]*(x@W)[j][o]  (fp32, exact self-loop path)
// sTq[o][j] = e4m3(64 * ssc[j][o]) (transposed fp8 B operand; /64 in epilogue)
__global__ __launch_bounds__(256) void k_support(const float* __restrict__ x,
                                                 const float* __restrict__ W,
                                                 const float* __restrict__ dinv,
                                                 float* __restrict__ ssc,
                                                 unsigned char* __restrict__ sTq) {
  const int r = threadIdx.x >> 5;            // 0..7
  const int c4 = (threadIdx.x & 31) << 2;    // 0..124
  const size_t row = (size_t)blockIdx.x * 8 + r;
  const float* xr = x + row * IN_F;
  float a0 = 0.f, a1 = 0.f, a2 = 0.f, a3 = 0.f;
#pragma unroll 4
  for (int k = 0; k < IN_F; ++k) {
    float xv = xr[k];
    float4 wv = *reinterpret_cast<const float4*>(W + (size_t)k * OUT_F + c4);
    a0 = fmaf(xv, wv.x, a0); a1 = fmaf(xv, wv.y, a1);
    a2 = fmaf(xv, wv.z, a2); a3 = fmaf(xv, wv.w, a3);
  }
  const float d = dinv[row];
  a0 *= d; a1 *= d; a2 *= d; a3 *= d;
  *reinterpret_cast<float4*>(ssc + row * OUT_F + c4) = make_float4(a0, a1, a2, a3);
  unsigned int u01 = (unsigned)__builtin_amdgcn_cvt_pk_fp8_f32(a0 * 64.f, a1 * 64.f, 0, false);
  unsigned int u23 = (unsigned)__builtin_amdgcn_cvt_pk_fp8_f32(a2 * 64.f, a3 * 64.f, 0, false);
  sTq[(size_t)(c4 + 0) * N_NODES + row] = (unsigned char)(u01 & 0xff);
  sTq[(size_t)(c4 + 1) * N_NODES + row] = (unsigned char)((u01 >> 8) & 0xff);
  sTq[(size_t)(c4 + 2) * N_NODES + row] = (unsigned char)(u23 & 0xff);
  sTq[(size_t)(c4 + 3) * N_NODES + row] = (unsigned char)((u23 >> 8) & 0xff);
}

// ----------------------------------------------------------------- big GEMM
// out[i][o] = dinv[i]*( (1/64)*sum_j adjq[i][j]*sTq[o][j] + ssc[i][o] ) + b[o]
// BM=16 rows/block, grid 768 = 3 blocks/CU (12 waves/CU MLP).
// A: 3-slot LDS ring (3 x 4 KB), staged 2 ahead via global_load_lds
//    (linear dest, XOR-preswizzled source; read applies same XOR).
// B: triple-buffered register prefetch 2 ahead from L2-resident sTq.
// Counted vmcnt(17) — never drains the pipeline in the main loop.
// Race-safe: barrier separates compute(t-1) from stage(t+2) into same slot.
__global__ __launch_bounds__(256, 3) void k_gemm(const unsigned char* __restrict__ adjq,
                                                 const unsigned char* __restrict__ sTq,
                                                 const float* __restrict__ ssc,
                                                 const float* __restrict__ dinv,
                                                 const float* __restrict__ bias,
                                                 float* __restrict__ out) {
  __shared__ __align__(16) char A_lds[3 * 4096];

  const int tid = threadIdx.x;
  const int lane = tid & 63;
  const int wv = tid >> 6;
  const size_t rowbase = (size_t)blockIdx.x * BM;
  const int ph = blockIdx.x % NSTEPS;     // K-phase stagger

  const int g = lane >> 4;       // k-group 0..3
  const int c15 = lane & 15;     // A-row / B-col within 16

  // stage map: row r = wv*4 + (lane>>4), chunk c = lane&15 (16 B units)
  const int srow = wv * 4 + (lane >> 4);
  const int schunk = (c15 ^ (srow & 7)) << 4;
  const unsigned char* abase = adjq + (rowbase + srow) * (size_t)N_NODES + schunk;

  const unsigned char* bptr = sTq + (size_t)(wv * 32 + c15) * N_NODES + g * 8;

  f32x4 acc[2];
  acc[0] = (f32x4){0.f, 0.f, 0.f, 0.f};
  acc[1] = (f32x4){0.f, 0.f, 0.f, 0.f};

  i64 b0[2][8], b1[2][8], b2[2][8];   // 96 VGPR triple-buffer

  auto phys = [&](int t) { int c = t + ph; if (c >= NSTEPS) c -= NSTEPS; return c; };

  auto stageA = [&](int t, int slot) {
    const int sc = phys(t);
    __builtin_amdgcn_global_load_lds(
        (__attribute__((address_space(1))) void*)(abase + (size_t)sc * BK),
        (__attribute__((address_space(3))) void*)(A_lds + slot * 4096 + srow * 256 +
                                                  (c15 << 4)),
        16, 0, 0);
  };
  auto loadB = [&](int t, i64 (&B)[2][8]) {
    const int sc = phys(t);
#pragma unroll
    for (int nt = 0; nt < 2; ++nt)
#pragma unroll
      for (int kt = 0; kt < 8; ++kt)
        B[nt][kt] = *(const i64*)(bptr + (size_t)nt * 16 * N_NODES +
                                  (size_t)sc * BK + kt * 32);
  };
  auto compute = [&](int slot, i64 (&B)[2][8]) {
    const char* Ab = A_lds + slot * 4096 + c15 * 256;
    const int key = c15 & 7;
#pragma unroll
    for (int kt = 0; kt < 8; ++kt) {
      i64 a = *(const i64*)(Ab + (((kt * 2 + (g >> 1)) ^ key) << 4) + ((g & 1) << 3));
      acc[0] = __builtin_amdgcn_mfma_f32_16x16x32_fp8_fp8(a, B[0][kt], acc[0], 0, 0, 0);
      acc[1] = __builtin_amdgcn_mfma_f32_16x16x32_fp8_fp8(a, B[1][kt], acc[1], 0, 0, 0);
    }
  };

// Per step t (slot S): wait counted; barrier (separates prev compute from the
// slot overwrite); prefetch loadB(t+2)+stageA(t+2); compute(t).
// Steady-state outstanding at wait: loadB(t+1)[16] + stageA(t+1)[1] = 17.
#define GSTEP(t, S, CUR, NX2, DOPRE, VMC)                        \
  {                                                              \
    asm volatile("s_waitcnt vmcnt(" VMC ")" ::: "memory");       \
    __builtin_amdgcn_s_barrier();                                \
    __builtin_amdgcn_sched_barrier(0);                           \
    if (DOPRE) {                                                 \
      loadB((t) + 2, NX2);                                       \
      __builtin_amdgcn_sched_barrier(0);                         \
      stageA((t) + 2, ((S) + 2) % 3);                            \
      __builtin_amdgcn_sched_barrier(0);                         \
    }                                                            \
    compute((S), CUR);                                           \
  }

  // prologue (order pinned for the count): A(0),B(0),A(1),B(1)
  stageA(0, 0);
  __builtin_amdgcn_sched_barrier(0);
  loadB(0, b0);
  __builtin_amdgcn_sched_barrier(0);
  stageA(1, 1);
  __builtin_amdgcn_sched_barrier(0);
  loadB(1, b1);
  __builtin_amdgcn_sched_barrier(0);

  for (int t = 0; t < NSTEPS - 3; t += 3) {
    GSTEP(t, 0, b0, b2, 1, "17");
    GSTEP(t + 1, 1, b1, b0, 1, "17");
    GSTEP(t + 2, 2, b2, b1, 1, "17");
  }
  GSTEP(NSTEPS - 3, 0, b0, b2, 1, "17");   // t=45, prefetch 47
  GSTEP(NSTEPS - 2, 1, b1, b0, 0, "17");   // t=46
  GSTEP(NSTEPS - 1, 2, b2, b1, 0, "0");    // t=47
#undef GSTEP

  // epilogue: C/D layout col=lane&15, row=(lane>>4)*4+r
  const float inv64 = 0.015625f;
#pragma unroll
  for (int nt = 0; nt < 2; ++nt) {
    const int col = wv * 32 + nt * 16 + c15;
    const float bv = bias[col];
#pragma unroll
    for (int r = 0; r < 4; ++r) {
      const size_t orow = rowbase + (g << 2) + r;
      const float d = dinv[orow];
      out[orow * OUT_F + col] =
          fmaf(d, acc[nt][r] * inv64 + ssc[orow * OUT_F + col], bv);
    }
  }
}

extern "C" void kernel_launch(void* const* d_in, const int* in_sizes, int n_in,
                              void* d_out, int out_size, void* d_ws, size_t ws_size,
                              hipStream_t stream) {
  const float* x   = (const float*)d_in[0];
  const float* adj = (const float*)d_in[1];
  const float* W   = (const float*)d_in[2];
  const float* b   = (const float*)d_in[3];
  float* out = (float*)d_out;

  // ws layout: dinv 48K | ssc 6.0M | sTq 1.5M | adjq 151M   (~159 MB)
  char* ws = (char*)d_ws;
  float* dinv         = (float*)ws;
  float* ssc          = (float*)(ws + 49152);
  unsigned char* sTq  = (unsigned char*)(ws + 49152 + 6291456);
  unsigned char* adjq = (unsigned char*)(ws + 49152 + 6291456 + 1572864);

  k_deg<<<N_NODES, 256, 0, stream>>>(adj, dinv, (unsigned int*)adjq);
  k_support<<<N_NODES / 8, 256, 0, stream>>>(x, W, dinv, ssc, sTq);
  k_gemm<<<N_NODES / BM, 256, 0, stream>>>(adjq, sTq, ssc, dinv, b, out);
}

// Round 9
// 275.223 us; speedup vs baseline: 1.6078x; 1.6078x over previous
//
#include <hip/hip_runtime.h>
#include <cstdint>
#include <cstddef>

#define N_NODES 12288
#define IN_F 256
#define OUT_F 128
#define BM 48
#define BK 256                      /* K elements per step = bytes (fp8) */
#define NSTEPS (N_NODES / BK)       /* 48 */
#define A_BYTES (BM * BK)           /* 12288 */
#define B_BYTES (OUT_F * BK)        /* 32768 */
#define SLOT (A_BYTES + B_BYTES)    /* 45056 */

#define DEG_BLOCKS 2048
#define DEG_WAVES (DEG_BLOCKS * 4)           /* 8192 */
#define N_CHUNKS (N_NODES * N_NODES / 256)   /* 589824 1KB-chunks */
#define CHUNKS_PER_ROW (N_NODES / 256)       /* 48 */
#define DEG_ITERS (N_CHUNKS / DEG_WAVES)     /* 72 */

using f32x4 = __attribute__((ext_vector_type(4))) float;
typedef long long i64;

// ---------------------------------------------------------------- deg pass
// m13-style flat stream: wave gw handles 1KB chunks c = gw + i*8192, so at
// any instant the whole chip reads ONE contiguous sweeping window (the
// pattern that reaches ~6.3 TB/s) instead of 2048 scattered row-streams.
// Each aligned 1KB chunk lies inside one 48KB row -> one deterministic
// per-chunk partial sum (no atomics). Also writes adjq = e4m3(adj).
__global__ __launch_bounds__(256) void k_deg(const float* __restrict__ adj,
                                             unsigned int* __restrict__ adjq,
                                             float* __restrict__ partials) {
  const int lane = threadIdx.x & 63;
  const int wv = threadIdx.x >> 6;
  const int gw = blockIdx.x * 4 + wv;   // 0..8191
#pragma unroll 4
  for (int i = 0; i < DEG_ITERS; ++i) {
    const size_t c = (size_t)gw + (size_t)i * DEG_WAVES;  // chunk id
    const size_t f4 = c * 64 + lane;                      // float4 index
    f32x4 v = *(reinterpret_cast<const f32x4*>(adj) + f4);
    unsigned int u = (unsigned)__builtin_amdgcn_cvt_pk_fp8_f32(v[0], v[1], 0, false);
    u = (unsigned)__builtin_amdgcn_cvt_pk_fp8_f32(v[2], v[3], (int)u, true);
    adjq[f4] = u;
    float s = (v[0] + v[1]) + (v[2] + v[3]);
    s += __shfl_xor(s, 1, 64);
    s += __shfl_xor(s, 2, 64);
    s += __shfl_xor(s, 4, 64);
    s += __shfl_xor(s, 8, 64);
    s += __shfl_xor(s, 16, 64);
    s += __shfl_xor(s, 32, 64);
    if (lane == 0) partials[c] = s;
  }
}

// ----------------------------------------------------------------- dinv
// dinv[r] = rsqrt(1 + sum_{k<48} partials[r*48+k])
__global__ __launch_bounds__(256) void k_dinv(const float* __restrict__ partials,
                                              float* __restrict__ dinv) {
  const int r = blockIdx.x * 256 + threadIdx.x;
  const float* p = partials + (size_t)r * CHUNKS_PER_ROW;
  float s = 0.f;
#pragma unroll
  for (int k = 0; k < CHUNKS_PER_ROW; ++k) s += p[k];
  dinv[r] = rsqrtf(1.f + s);
}

// ------------------------------------------------------------- support pass
// ssc[j][o] = dinv[j]*(x@W)[j][o]  (fp32, exact self-loop path)
// sTq[o][j] = e4m3(64 * ssc[j][o]) (transposed fp8 B operand; /64 in epilogue)
__global__ __launch_bounds__(256) void k_support(const float* __restrict__ x,
                                                 const float* __restrict__ W,
                                                 const float* __restrict__ dinv,
                                                 float* __restrict__ ssc,
                                                 unsigned char* __restrict__ sTq) {
  const int r = threadIdx.x >> 5;            // 0..7
  const int c4 = (threadIdx.x & 31) << 2;    // 0..124
  const size_t row = (size_t)blockIdx.x * 8 + r;
  const float* xr = x + row * IN_F;
  float a0 = 0.f, a1 = 0.f, a2 = 0.f, a3 = 0.f;
#pragma unroll 4
  for (int k = 0; k < IN_F; ++k) {
    float xv = xr[k];
    float4 wv = *reinterpret_cast<const float4*>(W + (size_t)k * OUT_F + c4);
    a0 = fmaf(xv, wv.x, a0); a1 = fmaf(xv, wv.y, a1);
    a2 = fmaf(xv, wv.z, a2); a3 = fmaf(xv, wv.w, a3);
  }
  const float d = dinv[row];
  a0 *= d; a1 *= d; a2 *= d; a3 *= d;
  *reinterpret_cast<float4*>(ssc + row * OUT_F + c4) = make_float4(a0, a1, a2, a3);
  unsigned int u01 = (unsigned)__builtin_amdgcn_cvt_pk_fp8_f32(a0 * 64.f, a1 * 64.f, 0, false);
  unsigned int u23 = (unsigned)__builtin_amdgcn_cvt_pk_fp8_f32(a2 * 64.f, a3 * 64.f, 0, false);
  sTq[(size_t)(c4 + 0) * N_NODES + row] = (unsigned char)(u01 & 0xff);
  sTq[(size_t)(c4 + 1) * N_NODES + row] = (unsigned char)((u01 >> 8) & 0xff);
  sTq[(size_t)(c4 + 2) * N_NODES + row] = (unsigned char)(u23 & 0xff);
  sTq[(size_t)(c4 + 3) * N_NODES + row] = (unsigned char)((u23 >> 8) & 0xff);
}

// ----------------------------------------------------------------- big GEMM
// (verbatim R5 — 268 µs config)
// out[i][o] = dinv[i]*( (1/64)*sum_j adjq[i][j]*sTq[o][j] + ssc[i][o] ) + b[o]
__global__ __launch_bounds__(256, 1) void k_gemm(const unsigned char* __restrict__ adjq,
                                                 const unsigned char* __restrict__ sTq,
                                                 const float* __restrict__ ssc,
                                                 const float* __restrict__ dinv,
                                                 const float* __restrict__ bias,
                                                 float* __restrict__ out) {
  __shared__ __align__(16) char LDSBUF[2 * SLOT];   // 88 KB

  const int tid = threadIdx.x;
  const int lane = tid & 63;
  const int wv = tid >> 6;
  const size_t rowbase = (size_t)blockIdx.x * BM;

  const int g = lane >> 4;       // k-group 0..3 (also row-within-instr on stage)
  const int c15 = lane & 15;     // fragment row/col within 16
  const int dr = c15 & 7;        // read-side XOR key

  f32x4 acc[3][2];
#pragma unroll
  for (int mt = 0; mt < 3; ++mt)
#pragma unroll
    for (int nt = 0; nt < 2; ++nt) acc[mt][nt] = (f32x4){0.f, 0.f, 0.f, 0.f};

  auto stage = [&](int s, int slot) {
    char* L = LDSBUF + slot * SLOT;
#pragma unroll
    for (int j = 0; j < 3; ++j) {
      const int instr = wv * 3 + j;
      const int r = instr * 4 + g;
      const int chunk = c15 ^ (r & 7);
      const unsigned char* src = adjq + (rowbase + r) * (size_t)N_NODES +
                                 (size_t)s * BK + chunk * 16;
      __builtin_amdgcn_global_load_lds(
          (__attribute__((address_space(1))) void*)src,
          (__attribute__((address_space(3))) void*)(L + instr * 1024 + lane * 16),
          16, 0, 0);
    }
#pragma unroll
    for (int j = 0; j < 8; ++j) {
      const int instr = wv * 8 + j;
      const int o = instr * 4 + g;
      const int chunk = c15 ^ (o & 7);
      const unsigned char* src = sTq + (size_t)o * N_NODES + (size_t)s * BK + chunk * 16;
      __builtin_amdgcn_global_load_lds(
          (__attribute__((address_space(1))) void*)src,
          (__attribute__((address_space(3))) void*)(L + A_BYTES + instr * 1024 + lane * 16),
          16, 0, 0);
    }
  };

  auto compute = [&](int slot) {
    const char* LA = LDSBUF + slot * SLOT;
    const char* LB = LA + A_BYTES;
    const int bcol0 = wv * 32 + c15;
#pragma unroll
    for (int kt = 0; kt < 8; ++kt) {
      const int phys = (((kt * 2 + (g >> 1)) ^ dr) << 4) + ((g & 1) << 3);
      i64 a0 = *(const i64*)(LA + (0 * 16 + c15) * 256 + phys);
      i64 a1 = *(const i64*)(LA + (1 * 16 + c15) * 256 + phys);
      i64 a2 = *(const i64*)(LA + (2 * 16 + c15) * 256 + phys);
      i64 b0 = *(const i64*)(LB + (size_t)(bcol0)*256 + phys);
      i64 b1 = *(const i64*)(LB + (size_t)(bcol0 + 16) * 256 + phys);
      acc[0][0] = __builtin_amdgcn_mfma_f32_16x16x32_fp8_fp8(a0, b0, acc[0][0], 0, 0, 0);
      acc[0][1] = __builtin_amdgcn_mfma_f32_16x16x32_fp8_fp8(a0, b1, acc[0][1], 0, 0, 0);
      acc[1][0] = __builtin_amdgcn_mfma_f32_16x16x32_fp8_fp8(a1, b0, acc[1][0], 0, 0, 0);
      acc[1][1] = __builtin_amdgcn_mfma_f32_16x16x32_fp8_fp8(a1, b1, acc[1][1], 0, 0, 0);
      acc[2][0] = __builtin_amdgcn_mfma_f32_16x16x32_fp8_fp8(a2, b0, acc[2][0], 0, 0, 0);
      acc[2][1] = __builtin_amdgcn_mfma_f32_16x16x32_fp8_fp8(a2, b1, acc[2][1], 0, 0, 0);
    }
  };

#define GSTEP(s, VMC, DOSTAGE)                                   \
  {                                                              \
    asm volatile("s_waitcnt vmcnt(" VMC ")" ::: "memory");       \
    __builtin_amdgcn_s_barrier();                                \
    __builtin_amdgcn_sched_barrier(0);                           \
    compute((s) & 1);                                            \
    __builtin_amdgcn_s_barrier();                                \
    __builtin_amdgcn_sched_barrier(0);                           \
    if (DOSTAGE) stage((s) + 2, (s) & 1);                        \
    __builtin_amdgcn_sched_barrier(0);                           \
  }

  stage(0, 0);
  __builtin_amdgcn_sched_barrier(0);
  stage(1, 1);

  for (int s = 0; s < NSTEPS - 2; ++s) GSTEP(s, "11", 1);
  GSTEP(NSTEPS - 2, "11", 0);
  GSTEP(NSTEPS - 1, "0", 0);
#undef GSTEP

  const float inv64 = 0.015625f;
  const int col0 = wv * 32 + c15;
#pragma unroll
  for (int mt = 0; mt < 3; ++mt) {
#pragma unroll
    for (int nt = 0; nt < 2; ++nt) {
      const int col = col0 + nt * 16;
      const float bv = bias[col];
#pragma unroll
      for (int r = 0; r < 4; ++r) {
        const size_t orow = rowbase + mt * 16 + (g << 2) + r;
        const float d = dinv[orow];
        out[orow * OUT_F + col] =
            fmaf(d, acc[mt][nt][r] * inv64 + ssc[orow * OUT_F + col], bv);
      }
    }
  }
}

extern "C" void kernel_launch(void* const* d_in, const int* in_sizes, int n_in,
                              void* d_out, int out_size, void* d_ws, size_t ws_size,
                              hipStream_t stream) {
  const float* x   = (const float*)d_in[0];
  const float* adj = (const float*)d_in[1];
  const float* W   = (const float*)d_in[2];
  const float* b   = (const float*)d_in[3];
  float* out = (float*)d_out;

  // ws: dinv 48K | ssc 6.0M | sTq 1.5M | adjq 151M | partials 2.4M (~162 MB)
  char* ws = (char*)d_ws;
  float* dinv         = (float*)ws;
  float* ssc          = (float*)(ws + 49152);
  unsigned char* sTq  = (unsigned char*)(ws + 49152 + 6291456);
  unsigned char* adjq = (unsigned char*)(ws + 49152 + 6291456 + 1572864);
  float* partials     = (float*)(ws + 49152 + 6291456 + 1572864 + 150994944);

  k_deg<<<DEG_BLOCKS, 256, 0, stream>>>(adj, (unsigned int*)adjq, partials);
  k_dinv<<<N_NODES / 256, 256, 0, stream>>>(partials, dinv);
  k_support<<<N_NODES / 8, 256, 0, stream>>>(x, W, dinv, ssc, sTq);
  k_gemm<<<N_NODES / BM, 256, 0, stream>>>(adjq, sTq, ssc, dinv, b, out);
}